// Round 11
// baseline (72.483 us; speedup 1.0000x reference)
//
#include <hip/hip_runtime.h>
#include <hip/hip_bf16.h>

#define KDIM 256
#define NTOT 131072
#define PN   65536        // 256*256
#define NB   256          // split-K blocks
#define RPB  512          // rows per block = NTOT/NB
#define CHROWS 16         // rows per staging chunk
#define CH   (CHROWS*KDIM) // floats per chunk per matrix
#define NTL  16           // compute tiles per block (32 rows each)
#define EPSF 2.220446049250313e-16f

typedef float f32x4 __attribute__((ext_vector_type(4)));
typedef __bf16 bf16x8 __attribute__((ext_vector_type(8)));

__device__ __forceinline__ unsigned short f2bf(float x){
  unsigned u = __float_as_uint(x);
  u += 0x7fffu + ((u >> 16) & 1u);   // round-to-nearest-even
  return (unsigned short)(u >> 16);
}
__device__ __forceinline__ unsigned pk2(float lo, float hi){
  return (unsigned)f2bf(lo) | ((unsigned)f2bf(hi) << 16);
}
__device__ __forceinline__ float bf2f(unsigned short u){
  return __uint_as_float((unsigned)u << 16);
}
// XOR swizzle on byte-bits 4..6 of a 64B-row layout.
// Applied to the FULL linear address everywhere (write and read).
__device__ __forceinline__ int swz(int i){ return (((i >> 1) ^ (i >> 4)) & 7) << 4; }

struct Stage { f32x4 r0, r1; };   // two rows, same 4-col quad, ONE matrix (8 VGPRs)

__device__ __forceinline__ void stage_load(Stage& s, const float* src, long off){
  s.r0 = *(const f32x4*)(src + off);
  s.r1 = *(const f32x4*)(src + off + KDIM);
}

__device__ __forceinline__ void stage_store(const Stage& s, char* tile, const int* offW){
#pragma unroll
  for (int m = 0; m < 4; ++m)
    *(unsigned*)(tile + offW[m]) = pk2(s.r0[m], s.r1[m]);
}

__device__ __forceinline__ void compute_t(const char* As, const char* Bs,
                                          const int* offA, const int* offB,
                                          f32x4 (&acc)[4][4])
{
  bf16x8 af[4], bfr[4];
#pragma unroll
  for (int m = 0; m < 4; ++m) af[m]  = *(const bf16x8*)(As + offA[m]);
#pragma unroll
  for (int n = 0; n < 4; ++n) bfr[n] = *(const bf16x8*)(Bs + offB[n]);
#pragma unroll
  for (int m = 0; m < 4; ++m)
#pragma unroll
    for (int n = 0; n < 4; ++n)
      acc[m][n] = __builtin_amdgcn_mfma_f32_16x16x32_bf16(af[m], bfr[n], acc[m][n], 0, 0, 0);
}

__device__ __forceinline__ void lds_fence_barrier(){
  __builtin_amdgcn_sched_barrier(0);
  asm volatile("s_waitcnt lgkmcnt(0)");
  __builtin_amdgcn_sched_barrier(0);
  __builtin_amdgcn_s_barrier();              // raw barrier: no vmcnt drain
  __builtin_amdgcn_sched_barrier(0);
}

// K1: partial_b[256][256] (bf16) = sum over this block's 512-row N-chunk of v1[n][i]*v2[n][j]
// Block 0 also zeroes csum (consumed only by k_reduce, which launches after).
__global__ __launch_bounds__(1024) void k_gemm(const float* __restrict__ v1,
                                               const float* __restrict__ v2,
                                               unsigned short* __restrict__ part,
                                               float* __restrict__ csum)
{
  __shared__ char sm[65536];   // tile T0: A@0 B@16K ; tile T1: A@32K B@48K (32 n-rows, 64B i-rows)
  const int t    = threadIdx.x;
  const int b    = blockIdx.x;
  if (b == 0 && t < 256) csum[t] = 0.f;
  const int lane = t & 63, wid = t >> 6;
  const int di   = lane & 15, g = lane >> 4;
  const int wr   = wid >> 2, wc = wid & 3;
  const int i0   = wr * 64, j0 = wc * 64;   // 4x4 waves, 64x64 output tile each

  // staging assignment: 512 threads per matrix.
  // p = t&7 (row-pair), q = (t>>3)&63 (col-quad): p varies ACROSS lanes so the
  // ds_write bank = 16*(i&1) ^ p ^ 4*e(i) spreads 2-way (free) instead of the
  // old p-uniform mapping's 8-way (was 6 extra cy on every staging write).
  const int mtx = t >> 9;            // 0: v1/A, 1: v2/B
  const int p   = t & 7;             // row-pair within 16-row chunk
  const int q   = (t >> 3) & 63;     // 4-col quad
  const float* src = (mtx ? v2 : v1) + ((long)b * RPB + 2 * p) * KDIM + 4 * q;
  const int sbase = mtx * 16384;     // A sub-tile at +0, B at +16K within a tile buffer

  int offW0[4], offW1[4], offA[4], offB[4];
#pragma unroll
  for (int m = 0; m < 4; ++m){
    const int i   = 4*q + m;
    const int lin = (i << 6) + (p << 2);
    offW0[m] = sbase + ( lin        ^ swz(i));   // even chunk -> words 0..7
    offW1[m] = sbase + ((lin + 32)  ^ swz(i));   // odd chunk  -> words 8..15
  }
#pragma unroll
  for (int m = 0; m < 4; ++m){ int i = i0 + 16*m + di; offA[m] = ((i << 6) + (g << 4)) ^ swz(i); }
#pragma unroll
  for (int n = 0; n < 4; ++n){ int j = j0 + 16*n + di; offB[n] = ((j << 6) + (g << 4)) ^ swz(j); }

  f32x4 acc[4][4];
#pragma unroll
  for (int m = 0; m < 4; ++m)
#pragma unroll
    for (int n = 0; n < 4; ++n){ f32x4 z = {0.f,0.f,0.f,0.f}; acc[m][n] = z; }

  // --- prologue: fill tile 0 (chunks 0,1); leave chunks 2,3 in flight ---
  Stage S0, S1;
  stage_load(S0, src, 0L * CH);
  stage_load(S1, src, 1L * CH);
  stage_store(S0, sm, offW0);                // auto vmcnt(2): S1's loads stay in flight
  __builtin_amdgcn_sched_barrier(0);
  stage_load(S0, src, 2L * CH);
  __builtin_amdgcn_sched_barrier(0);
  stage_store(S1, sm, offW1);
  __builtin_amdgcn_sched_barrier(0);
  stage_load(S1, src, 3L * CH);
  lds_fence_barrier();

  // --- main loop: iter it computes tile it from T[it&1] FIRST (data ready, only
  //     lgkm-gated), THEN stores tile it+1 (vmcnt(2) overlap with other waves'
  //     compute) and issues chunks 2it+4, 2it+5. One barrier per iter.
#pragma unroll 2
  for (int it = 0; it < NTL - 2; ++it){
    char* Tc = sm + (it & 1) * 32768;
    char* Tn = sm + ((it + 1) & 1) * 32768;
    compute_t(Tc, Tc + 16384, offA, offB, acc);
    __builtin_amdgcn_sched_barrier(0);
    stage_store(S0, Tn, offW0);              // chunk 2it+2 (auto counted vmcnt(2))
    __builtin_amdgcn_sched_barrier(0);
    stage_load(S0, src, (long)(2*it + 4) * CH);
    __builtin_amdgcn_sched_barrier(0);
    stage_store(S1, Tn, offW1);              // chunk 2it+3
    __builtin_amdgcn_sched_barrier(0);
    stage_load(S1, src, (long)(2*it + 5) * CH);
    lds_fence_barrier();
  }

  // --- epilogue: compute tile 14, store last chunks 30,31, compute tile 15 ---
  {
    char* Tc = sm + ((NTL - 2) & 1) * 32768;   // T0
    char* Tn = sm + ((NTL - 1) & 1) * 32768;   // T1
    compute_t(Tc, Tc + 16384, offA, offB, acc);   // tile 14
    __builtin_amdgcn_sched_barrier(0);
    stage_store(S0, Tn, offW0);                // chunk 30
    stage_store(S1, Tn, offW1);                // chunk 31 (drains vmcnt, tail only)
    lds_fence_barrier();
    compute_t(Tn, Tn + 16384, offA, offB, acc);   // tile 15
  }

  unsigned short* op = part + (size_t)b * PN;
#pragma unroll
  for (int m = 0; m < 4; ++m)
#pragma unroll
    for (int n = 0; n < 4; ++n){
      const int i = i0 + 16*m + 4*g;
      const int j = j0 + 16*n + di;
#pragma unroll
      for (int r = 0; r < 4; ++r)
        op[(size_t)(i + r) * KDIM + j] = f2bf(acc[m][n][r]);
    }
}

// K2: P = sum_b part_b ; row sums rsum[gr]; (atomic) col sums csum[j].
// Vectorized: ushort4 loads (8B/lane), 16-way r-split, LDS combine.
// Block 0 zeroes out[0] (consumed only by k_loss, launched after).
__global__ __launch_bounds__(1024) void k_reduce(const unsigned short* __restrict__ part,
                                                 float* __restrict__ P,
                                                 float* __restrict__ rsum,
                                                 float* __restrict__ csum,
                                                 float* __restrict__ out)
{
  __shared__ float red[16][256];
  const int gr = blockIdx.x;            // P row (i)
  const int t  = threadIdx.x;
  const int q  = t >> 6;                // 0..15 r-split
  const int jq = t & 63;                // j-quad
  f32x4 a = {0.f, 0.f, 0.f, 0.f};
  const unsigned short* p = part + (size_t)(q * 16) * PN + gr * KDIM + 4 * jq;
  for (int k = 0; k < 16; ++k){
    const ushort4 u = *(const ushort4*)(p + (size_t)k * PN);
    a[0] += bf2f(u.x); a[1] += bf2f(u.y); a[2] += bf2f(u.z); a[3] += bf2f(u.w);
  }
  *(f32x4*)&red[q][4 * jq] = a;
  __syncthreads();
  float v = 0.f;
  if (t < 256){
#pragma unroll
    for (int qq = 0; qq < 16; ++qq) v += red[qq][t];
    P[gr * KDIM + t] = v;
    atomicAdd(&csum[t], v);
  }
  __syncthreads();
  if (t < 256) red[0][t] = v;
  __syncthreads();
  for (int st = 128; st > 0; st >>= 1){
    if (t < st) red[0][t] += red[0][t + st];
    __syncthreads();
  }
  if (t == 0){
    rsum[gr] = red[0][0];
    if (gr == 0) out[0] = 0.f;
  }
}

// K3 (fused marg+loss): each block recomputes S and lm[256] locally (cheap),
// then its slice of loss = sum_ij -q*(log q - 10*(lm_i + lm_j)), q=(P_ij+P_ji)/(2S).
// 128 blocks x 256 threads, one atomicAdd per block into out[0].
__global__ __launch_bounds__(256) void k_loss(const float* __restrict__ P,
                                              const float* __restrict__ rsum,
                                              const float* __restrict__ csum,
                                              float* __restrict__ out)
{
  __shared__ float lm[256];
  __shared__ float red[256];
  const int t = threadIdx.x;
  const float ri = rsum[t];
  red[t] = ri; __syncthreads();
  for (int st = 128; st > 0; st >>= 1){
    if (t < st) red[t] += red[t + st];
    __syncthreads();
  }
  const float S = red[0];
  const float inv2S = 0.5f / S;
  lm[t] = logf(fmaxf((ri + csum[t]) * inv2S, EPSF));
  __syncthreads();

  float acc = 0.f;
  const int base = blockIdx.x * 512;
#pragma unroll
  for (int e = base + t; e < base + 512; e += 256){
    const int i = e >> 8, j = e & 255;
    float qv = (P[i * KDIM + j] + P[j * KDIM + i]) * inv2S;
    qv = fmaxf(qv, EPSF);
    acc += -qv * (logf(qv) - 10.0f * (lm[i] + lm[j]));
  }
  red[t] = acc; __syncthreads();
  for (int st = 128; st > 0; st >>= 1){
    if (t < st) red[t] += red[t + st];
    __syncthreads();
  }
  if (t == 0) atomicAdd(out, red[0]);
}

extern "C" void kernel_launch(void* const* d_in, const int* in_sizes, int n_in,
                              void* d_out, int out_size, void* d_ws, size_t ws_size,
                              hipStream_t stream) {
  const float* v1 = (const float*)d_in[0];
  const float* v2 = (const float*)d_in[1];
  float* out = (float*)d_out;
  char*  wsc = (char*)d_ws;

  unsigned short* part = (unsigned short*)wsc;                 // NB*PN bf16 = 32 MB
  float* P    = (float*)(wsc + (size_t)NB * PN * 2);           // 256 KB
  float* rsum = P + PN;
  float* csum = rsum + 256;

  k_gemm  <<<NB, 1024, 0, stream>>>(v1, v2, part, csum);
  k_reduce<<<256, 1024, 0, stream>>>(part, P, rsum, csum, out);
  k_loss  <<<128, 256, 0, stream>>>(P, rsum, csum, out);
}

// Round 12
// 69.990 us; speedup vs baseline: 1.0356x; 1.0356x over previous
//
#include <hip/hip_runtime.h>
#include <hip/hip_bf16.h>

#define KDIM 256
#define NTOT 131072
#define PN   65536        // 256*256
#define NB   256          // split-K blocks
#define RPB  512          // rows per block = NTOT/NB
#define CHROWS 16         // rows per staging chunk
#define CH   (CHROWS*KDIM) // floats per chunk per matrix
#define NTL  16           // compute tiles per block (32 rows each)
#define EPSF 2.220446049250313e-16f

typedef float f32x4 __attribute__((ext_vector_type(4)));
typedef __bf16 bf16x8 __attribute__((ext_vector_type(8)));
typedef unsigned short u16x8 __attribute__((ext_vector_type(8)));

__device__ __forceinline__ unsigned short f2bf(float x){
  unsigned u = __float_as_uint(x);
  u += 0x7fffu + ((u >> 16) & 1u);   // round-to-nearest-even
  return (unsigned short)(u >> 16);
}
__device__ __forceinline__ unsigned pk2(float lo, float hi){
  return (unsigned)f2bf(lo) | ((unsigned)f2bf(hi) << 16);
}
__device__ __forceinline__ float bf2f(unsigned short u){
  return __uint_as_float((unsigned)u << 16);
}
// XOR swizzle on byte-bits 4..6 of a 64B-row layout.
// Applied to the FULL linear address everywhere (write and read).
__device__ __forceinline__ int swz(int i){ return (((i >> 1) ^ (i >> 4)) & 7) << 4; }

struct Stage { f32x4 r0, r1; };   // two rows, same 4-col quad, ONE matrix (8 VGPRs)

__device__ __forceinline__ void stage_load(Stage& s, const float* src, long off){
  s.r0 = *(const f32x4*)(src + off);
  s.r1 = *(const f32x4*)(src + off + KDIM);
}

__device__ __forceinline__ void stage_store(const Stage& s, char* tile, const int* offW){
#pragma unroll
  for (int m = 0; m < 4; ++m)
    *(unsigned*)(tile + offW[m]) = pk2(s.r0[m], s.r1[m]);
}

__device__ __forceinline__ void compute_t(const char* As, const char* Bs,
                                          const int* offA, const int* offB,
                                          f32x4 (&acc)[4][4])
{
  bf16x8 af[4], bfr[4];
#pragma unroll
  for (int m = 0; m < 4; ++m) af[m]  = *(const bf16x8*)(As + offA[m]);
#pragma unroll
  for (int n = 0; n < 4; ++n) bfr[n] = *(const bf16x8*)(Bs + offB[n]);
#pragma unroll
  for (int m = 0; m < 4; ++m)
#pragma unroll
    for (int n = 0; n < 4; ++n)
      acc[m][n] = __builtin_amdgcn_mfma_f32_16x16x32_bf16(af[m], bfr[n], acc[m][n], 0, 0, 0);
}

__device__ __forceinline__ void lds_fence_barrier(){
  __builtin_amdgcn_sched_barrier(0);
  asm volatile("s_waitcnt lgkmcnt(0)");
  __builtin_amdgcn_sched_barrier(0);
  __builtin_amdgcn_s_barrier();              // raw barrier: no vmcnt drain
  __builtin_amdgcn_sched_barrier(0);
}

// K1: partial_b[256][256] (bf16) = sum over this block's 512-row N-chunk of v1[n][i]*v2[n][j]
// Block 0 also zeroes csum (consumed only by k_reduce, which launches after).
__global__ __launch_bounds__(1024) void k_gemm(const float* __restrict__ v1,
                                               const float* __restrict__ v2,
                                               unsigned short* __restrict__ part,
                                               float* __restrict__ csum)
{
  __shared__ char sm[65536];   // tile T0: A@0 B@16K ; tile T1: A@32K B@48K (32 n-rows, 64B i-rows)
  const int t    = threadIdx.x;
  const int b    = blockIdx.x;
  if (b == 0 && t < 256) csum[t] = 0.f;
  const int lane = t & 63, wid = t >> 6;
  const int di   = lane & 15, g = lane >> 4;
  const int wr   = wid >> 2, wc = wid & 3;
  const int i0   = wr * 64, j0 = wc * 64;   // 4x4 waves, 64x64 output tile each

  // staging assignment: 512 threads per matrix.
  // p = t&7 (row-pair), q = (t>>3)&63 (col-quad): p varies ACROSS lanes so the
  // ds_write bank spread is 2-way (free) instead of 8-way (R9 fix, verified
  // SQ_LDS_BANK_CONFLICT 3.15M -> 0 in R11).
  const int mtx = t >> 9;            // 0: v1/A, 1: v2/B
  const int p   = t & 7;             // row-pair within 16-row chunk
  const int q   = (t >> 3) & 63;     // 4-col quad
  const float* src = (mtx ? v2 : v1) + ((long)b * RPB + 2 * p) * KDIM + 4 * q;
  const int sbase = mtx * 16384;     // A sub-tile at +0, B at +16K within a tile buffer

  int offW0[4], offW1[4], offA[4], offB[4];
#pragma unroll
  for (int m = 0; m < 4; ++m){
    const int i   = 4*q + m;
    const int lin = (i << 6) + (p << 2);
    offW0[m] = sbase + ( lin        ^ swz(i));   // even chunk -> words 0..7
    offW1[m] = sbase + ((lin + 32)  ^ swz(i));   // odd chunk  -> words 8..15
  }
#pragma unroll
  for (int m = 0; m < 4; ++m){ int i = i0 + 16*m + di; offA[m] = ((i << 6) + (g << 4)) ^ swz(i); }
#pragma unroll
  for (int n = 0; n < 4; ++n){ int j = j0 + 16*n + di; offB[n] = ((j << 6) + (g << 4)) ^ swz(j); }

  f32x4 acc[4][4];
#pragma unroll
  for (int m = 0; m < 4; ++m)
#pragma unroll
    for (int n = 0; n < 4; ++n){ f32x4 z = {0.f,0.f,0.f,0.f}; acc[m][n] = z; }

  // --- prologue: fill tile 0 (chunks 0,1); leave chunks 2,3 in flight ---
  Stage S0, S1;
  stage_load(S0, src, 0L * CH);
  stage_load(S1, src, 1L * CH);
  stage_store(S0, sm, offW0);                // auto vmcnt(2): S1's loads stay in flight
  __builtin_amdgcn_sched_barrier(0);
  stage_load(S0, src, 2L * CH);
  __builtin_amdgcn_sched_barrier(0);
  stage_store(S1, sm, offW1);
  __builtin_amdgcn_sched_barrier(0);
  stage_load(S1, src, 3L * CH);
  lds_fence_barrier();

  // --- main loop (R6 ordering, A/B-verified ~4µs better than compute-first):
  //     stores land at iteration START (vmcnt(2) on 1-iter-old loads = no stall),
  //     next loads enter the memory queue early, ds_writes get the whole compute
  //     phase to retire before the lgkm fence. One barrier per iteration.
#pragma unroll 2
  for (int it = 0; it < NTL - 2; ++it){
    char* Tc = sm + (it & 1) * 32768;
    char* Tn = sm + ((it + 1) & 1) * 32768;
    stage_store(S0, Tn, offW0);              // chunk 2it+2 (auto counted vmcnt(2))
    __builtin_amdgcn_sched_barrier(0);
    stage_load(S0, src, (long)(2*it + 4) * CH);
    __builtin_amdgcn_sched_barrier(0);
    stage_store(S1, Tn, offW1);              // chunk 2it+3
    __builtin_amdgcn_sched_barrier(0);
    stage_load(S1, src, (long)(2*it + 5) * CH);
    __builtin_amdgcn_sched_barrier(0);
    compute_t(Tc, Tc + 16384, offA, offB, acc);
    lds_fence_barrier();
  }

  // --- epilogue: store last chunks 30,31 (no new issues), compute tiles 14,15 ---
  {
    char* Tc = sm + ((NTL - 2) & 1) * 32768;   // T0
    char* Tn = sm + ((NTL - 1) & 1) * 32768;   // T1
    stage_store(S0, Tn, offW0);                // chunk 30
    stage_store(S1, Tn, offW1);                // chunk 31 (drains vmcnt, tail only)
    __builtin_amdgcn_sched_barrier(0);
    compute_t(Tc, Tc + 16384, offA, offB, acc);   // tile 14
    lds_fence_barrier();
    compute_t(Tn, Tn + 16384, offA, offB, acc);   // tile 15
  }

  unsigned short* op = part + (size_t)b * PN;
#pragma unroll
  for (int m = 0; m < 4; ++m)
#pragma unroll
    for (int n = 0; n < 4; ++n){
      const int i = i0 + 16*m + 4*g;
      const int j = j0 + 16*n + di;
#pragma unroll
      for (int r = 0; r < 4; ++r)
        op[(size_t)(i + r) * KDIM + j] = f2bf(acc[m][n][r]);
    }
}

// K2: P = sum_b part_b ; row sums rsum[gr]; (atomic) col sums csum[j].
// u16x8 loads (16B/lane), 32-way b-split x 32 column-octets, LDS combine with
// 9-stride padding (gcd(9,32)=1 -> conflict-free scalar writes/reads).
// Block 0 zeroes out[0] (consumed only by k_loss, launched after).
__global__ __launch_bounds__(1024) void k_reduce(const unsigned short* __restrict__ part,
                                                 float* __restrict__ P,
                                                 float* __restrict__ rsum,
                                                 float* __restrict__ csum,
                                                 float* __restrict__ out)
{
  __shared__ float red[32][288];        // [b-group][col-octet*9 + elem]
  const int gr = blockIdx.x;            // P row (i)
  const int t  = threadIdx.x;
  const int q  = t >> 5;                // 0..31: group of 8 partial buffers
  const int o  = t & 31;                // 0..31: column octet (8 cols)
  float a[8];
#pragma unroll
  for (int e = 0; e < 8; ++e) a[e] = 0.f;
  const unsigned short* p = part + (size_t)(q * 8) * PN + gr * KDIM + o * 8;
#pragma unroll
  for (int k = 0; k < 8; ++k){
    const u16x8 u = *(const u16x8*)(p + (size_t)k * PN);
#pragma unroll
    for (int e = 0; e < 8; ++e) a[e] += bf2f(u[e]);
  }
#pragma unroll
  for (int e = 0; e < 8; ++e) red[q][o * 9 + e] = a[e];
  __syncthreads();
  float v = 0.f;
  if (t < 256){
    const int idx = (t >> 3) * 9 + (t & 7);
#pragma unroll
    for (int g = 0; g < 32; ++g) v += red[g][idx];
    P[gr * KDIM + t] = v;
    atomicAdd(&csum[t], v);
  }
  __syncthreads();
  if (t < 256) red[0][t] = v;
  __syncthreads();
  for (int st = 128; st > 0; st >>= 1){
    if (t < st) red[0][t] += red[0][t + st];
    __syncthreads();
  }
  if (t == 0){
    rsum[gr] = red[0][0];
    if (gr == 0) out[0] = 0.f;
  }
}

// K3 (fused marg+loss): each block recomputes S and lm[256] locally (cheap),
// then its slice of loss = sum_ij -q*(log q - 10*(lm_i + lm_j)), q=(P_ij+P_ji)/(2S).
// 128 blocks x 256 threads, one atomicAdd per block into out[0].
__global__ __launch_bounds__(256) void k_loss(const float* __restrict__ P,
                                              const float* __restrict__ rsum,
                                              const float* __restrict__ csum,
                                              float* __restrict__ out)
{
  __shared__ float lm[256];
  __shared__ float red[256];
  const int t = threadIdx.x;
  const float ri = rsum[t];
  red[t] = ri; __syncthreads();
  for (int st = 128; st > 0; st >>= 1){
    if (t < st) red[t] += red[t + st];
    __syncthreads();
  }
  const float S = red[0];
  const float inv2S = 0.5f / S;
  lm[t] = logf(fmaxf((ri + csum[t]) * inv2S, EPSF));
  __syncthreads();

  float acc = 0.f;
  const int base = blockIdx.x * 512;
#pragma unroll
  for (int e = base + t; e < base + 512; e += 256){
    const int i = e >> 8, j = e & 255;
    float qv = (P[i * KDIM + j] + P[j * KDIM + i]) * inv2S;
    qv = fmaxf(qv, EPSF);
    acc += -qv * (logf(qv) - 10.0f * (lm[i] + lm[j]));
  }
  red[t] = acc; __syncthreads();
  for (int st = 128; st > 0; st >>= 1){
    if (t < st) red[t] += red[t + st];
    __syncthreads();
  }
  if (t == 0) atomicAdd(out, red[0]);
}

extern "C" void kernel_launch(void* const* d_in, const int* in_sizes, int n_in,
                              void* d_out, int out_size, void* d_ws, size_t ws_size,
                              hipStream_t stream) {
  const float* v1 = (const float*)d_in[0];
  const float* v2 = (const float*)d_in[1];
  float* out = (float*)d_out;
  char*  wsc = (char*)d_ws;

  unsigned short* part = (unsigned short*)wsc;                 // NB*PN bf16 = 32 MB
  float* P    = (float*)(wsc + (size_t)NB * PN * 2);           // 256 KB
  float* rsum = P + PN;
  float* csum = rsum + 256;

  k_gemm  <<<NB, 1024, 0, stream>>>(v1, v2, part, csum);
  k_reduce<<<256, 1024, 0, stream>>>(part, P, rsum, csum, out);
  k_loss  <<<128, 256, 0, stream>>>(P, rsum, csum, out);
}